// Round 11
// baseline (652.198 us; speedup 1.0000x reference)
//
#include <hip/hip_runtime.h>
#include <hip/hip_fp16.h>

// GIN: 3 layers of {fused CSR-gather + (1+eps)*x + MLP(2x GEMM128 MFMA, BN, ReLU)},
// then fused lin1+ReLU+lin2+log_softmax head.
// N=100000, E=1.6M. Round 11: gather fused into the MLP kernel -- gathered rows go
// straight to the swizzled LDS tile (saves 51.2 MB global round-trip per layer).

#define PB 256    // partition blocks
#define MAXNB 512 // max buckets (N <= 131072)

typedef _Float16 f16x8 __attribute__((ext_vector_type(8)));
typedef float f32x4 __attribute__((ext_vector_type(4)));

struct H4 { __half2 a, b; };   // 8B fp16 quad

// ---------------------------------------------------------------------------
// Detect whether edge_index is int64 (all high words zero) or int32.
__global__ void detect_idx_kernel(const unsigned int* __restrict__ w, long long nOdd,
                                  int* __restrict__ flag) {
    __shared__ int any;
    if (threadIdx.x == 0) any = 0;
    __syncthreads();
    for (long long i = threadIdx.x; i < nOdd; i += blockDim.x) {
        if (w[2 * i + 1] != 0u) { any = 1; break; }
    }
    __syncthreads();
    if (threadIdx.x == 0) *flag = (any == 0) ? 1 : 0;   // 1 => int64 layout
}

// ---------------------------------------------------------------------------
// Pass 1: per-block LDS histogram over 256-node buckets -> cnt_mat[bucket][block].
__global__ __launch_bounds__(256) void p1_hist_kernel(
    const void* __restrict__ idx, long long E, const int* __restrict__ flag,
    int* __restrict__ cnt_mat, int NB) {
    __shared__ int h[MAXNB];
    for (int i = threadIdx.x; i < MAXNB; i += 256) h[i] = 0;
    __syncthreads();
    const long long C = (E + PB - 1) / PB;
    const long long lo = (long long)blockIdx.x * C;
    long long hi = lo + C; if (hi > E) hi = E;
    if (*flag) {
        const long long* pd = (const long long*)idx + E;
        for (long long i = lo + threadIdx.x; i < hi; i += 256)
            atomicAdd(&h[((int)pd[i]) >> 8], 1);
    } else {
        const int* pd = (const int*)idx + E;
        for (long long i = lo + threadIdx.x; i < hi; i += 256)
            atomicAdd(&h[pd[i] >> 8], 1);
    }
    __syncthreads();
    for (int i = threadIdx.x; i < NB; i += 256)
        cnt_mat[i * PB + blockIdx.x] = h[i];
}

// ---------------------------------------------------------------------------
// Per-bucket exclusive scan over the PB block-counts (in place) + bucket total.
__global__ __launch_bounds__(256) void scan_bucket_kernel(
    int* __restrict__ cnt_mat, int* __restrict__ btotal) {
    int k = blockIdx.x, t = threadIdx.x;
    __shared__ int sh[PB];
    int c = cnt_mat[k * PB + t];
    sh[t] = c;
    __syncthreads();
    for (int off = 1; off < PB; off <<= 1) {
        int v = (t >= off) ? sh[t - off] : 0;
        __syncthreads();
        sh[t] += v;
        __syncthreads();
    }
    cnt_mat[k * PB + t] = sh[t] - c;        // exclusive within bucket
    if (t == PB - 1) btotal[k] = sh[t];
}

// ---------------------------------------------------------------------------
// Exclusive scan of bucket totals -> bbase, boff; row_ptr[N] = E.
__global__ __launch_bounds__(512) void scan_btotal_kernel(
    const int* __restrict__ btotal, int* __restrict__ bbase, int* __restrict__ boff,
    int NB, int N, long long E, int* __restrict__ row_ptr) {
    int t = threadIdx.x;
    __shared__ int sh[512];
    int c = (t < NB) ? btotal[t] : 0;
    sh[t] = c;
    __syncthreads();
    for (int off = 1; off < 512; off <<= 1) {
        int v = (t >= off) ? sh[t - off] : 0;
        __syncthreads();
        sh[t] += v;
        __syncthreads();
    }
    int excl = sh[t] - c;
    if (t < NB) { bbase[t] = excl; boff[t] = excl; }
    if (t == 0) { boff[NB] = (int)E; row_ptr[N] = (int)E; }
}

// ---------------------------------------------------------------------------
// Pass 2: re-read chunk, LDS cursors seeded with global dense offsets, scatter
// (src,dst) into bucket-grouped bdata. Zero global atomics.
__global__ __launch_bounds__(256) void p2_scatter_kernel(
    const void* __restrict__ idx, long long E, const int* __restrict__ flag,
    const int* __restrict__ cnt_mat, const int* __restrict__ bbase,
    uint2* __restrict__ bdata, int NB) {
    __shared__ int cur[MAXNB];
    int b = blockIdx.x;
    for (int i = threadIdx.x; i < NB; i += 256)
        cur[i] = cnt_mat[i * PB + b] + bbase[i];
    __syncthreads();
    const long long C = (E + PB - 1) / PB;
    const long long lo = (long long)b * C;
    long long hi = lo + C; if (hi > E) hi = E;
    if (*flag) {
        const long long* ps = (const long long*)idx;
        const long long* pd = ps + E;
        for (long long i = lo + threadIdx.x; i < hi; i += 256) {
            int s = (int)ps[i], d = (int)pd[i];
            int r = atomicAdd(&cur[d >> 8], 1);
            bdata[r] = make_uint2((unsigned)s, (unsigned)d);
        }
    } else {
        const int* ps = (const int*)idx;
        const int* pd = ps + E;
        for (long long i = lo + threadIdx.x; i < hi; i += 256) {
            int s = ps[i], d = pd[i];
            int r = atomicAdd(&cur[d >> 8], 1);
            bdata[r] = make_uint2((unsigned)s, (unsigned)d);
        }
    }
}

// ---------------------------------------------------------------------------
// Per-bucket CSR finalize (256 nodes/bucket): LDS hist, LDS scan, row_ptr write,
// then place src into csr_src (16KB window per bucket, L2-absorbed).
__global__ __launch_bounds__(256) void csr_build_kernel(
    const uint2* __restrict__ bdata, const int* __restrict__ boff, int N,
    int* __restrict__ row_ptr, int* __restrict__ csr_src) {
    int b = blockIdx.x, t = threadIdx.x;
    int lo = boff[b], hi = boff[b + 1];
    int nb = b << 8;
    __shared__ int cnt[256];
    __shared__ int sh[256];
    cnt[t] = 0;
    __syncthreads();
    for (int i = lo + t; i < hi; i += 256)
        atomicAdd(&cnt[bdata[i].y & 255], 1);
    __syncthreads();
    int c = cnt[t];
    sh[t] = c;
    __syncthreads();
    for (int off = 1; off < 256; off <<= 1) {
        int v = (t >= off) ? sh[t - off] : 0;
        __syncthreads();
        sh[t] += v;
        __syncthreads();
    }
    int excl = sh[t] - c;
    if (nb + t < N) row_ptr[nb + t] = lo + excl;
    cnt[t] = excl;                 // cursor: local absolute position
    __syncthreads();
    for (int i = lo + t; i < hi; i += 256) {
        uint2 e = bdata[i];
        int p = atomicAdd(&cnt[e.y & 255], 1);
        csr_src[lo + p] = (int)e.x;
    }
}

// ---------------------------------------------------------------------------
// x fp32 [N,128] -> fp16.
__global__ void convert_x_kernel(__half* __restrict__ out, const float* __restrict__ in,
                                 int n4) {
    int i = blockIdx.x * blockDim.x + threadIdx.x;
    int stride = gridDim.x * blockDim.x;
    const float4* in4 = (const float4*)in;
    for (; i < n4; i += stride) {
        float4 v = in4[i];
        H4 h;
        h.a = __float22half2_rn(make_float2(v.x, v.y));
        h.b = __float22half2_rn(make_float2(v.z, v.w));
        *(H4*)(out + i * 4) = h;
    }
}

// ---------------------------------------------------------------------------
// Pack 7 fp32 [128][128] weight matrices (W1 l0..2, W2 l0..2, lin1) into fp16
// MFMA "A-operand" fragment order: pk[mat][((ks*8+ct)*64+lane)*8 + j] =
//   W[ks*32 + (lane>>4)*8 + j][ct*16 + (lane&15)]
__global__ void pack_w_kernel(__half* __restrict__ pk, const float* __restrict__ W1,
                              const float* __restrict__ W2, const float* __restrict__ lin1) {
    int t = blockIdx.x * blockDim.x + threadIdx.x;
    if (t >= 7 * 2048) return;
    int mat = t >> 11;
    int rem = t & 2047;
    int ks = rem >> 9;
    int ct = (rem >> 6) & 7;
    int lane = rem & 63;
    int g = lane >> 4, c = lane & 15;
    const float* src = (mat < 3) ? W1 + mat * 16384
                     : (mat < 6) ? W2 + (mat - 3) * 16384
                                 : lin1;
    __half* dst = pk + mat * 16384 + ((size_t)((ks * 8 + ct) * 64 + lane)) * 8;
#pragma unroll
    for (int j = 0; j < 8; ++j)
        dst[j] = (__half)src[(ks * 32 + g * 8 + j) * 128 + ct * 16 + c];
}

// ---------------------------------------------------------------------------
// Fused GIN layer: block owns 128 dst rows. Phase 1: gather (1+eps)*x[n]+sum
// x[nbr] (4x16-lane groups, uint4 reads, fp32 acc, shfl reduce) -> swizzled LDS.
// Phase 2: GEMM1 (MFMA) -> BN1+ReLU -> LDS -> GEMM2 -> BN2+ReLU -> global fp16.
__global__ __launch_bounds__(256) void gin_layer_kernel(
    const __half* __restrict__ in, const int* __restrict__ row_ptr,
    const int* __restrict__ csr, const float* __restrict__ eps, int layer,
    const __half* __restrict__ pk1, const float* __restrict__ b1,
    const float* __restrict__ g1, const float* __restrict__ bb1,
    const float* __restrict__ m1, const float* __restrict__ v1,
    const __half* __restrict__ pk2, const float* __restrict__ b2,
    const float* __restrict__ g2, const float* __restrict__ bb2,
    const float* __restrict__ m2, const float* __restrict__ v2,
    __half* __restrict__ out, int N) {
    __shared__ __half sA[128 * 128];
    __shared__ float sc1_s[128], sh1_s[128], sc2_s[128], sh2_s[128];

    const int tid = threadIdx.x;
    if (tid < 128) {
        int c = tid;
        float sc = g1[c] * rsqrtf(v1[c] + 1e-5f);
        sc1_s[c] = sc;
        sh1_s[c] = b1[c] * sc + bb1[c] - m1[c] * sc;
        sc = g2[c] * rsqrtf(v2[c] + 1e-5f);
        sc2_s[c] = sc;
        sh2_s[c] = b2[c] * sc + bb2[c] - m2[c] * sc;
    }

    const int base = blockIdx.x * 128;
    const int wave = tid >> 6;
    const int lane = tid & 63;
    const int g = lane >> 4;            // neighbor sub-group
    const int t = lane & 15;            // 16B chunk within row
    const float s = 1.0f + eps[layer];

    // ---- Phase 1: gather 32 rows per wave into swizzled LDS ----
    for (int k = 0; k < 32; ++k) {
        int row = wave * 32 + k;        // local row 0..127
        int r = base + row;
        int rc = (r < N) ? r : (N - 1); // clamp tail (outputs guarded later)
        int beg = row_ptr[rc], end = row_ptr[rc + 1];
        float2 a0 = make_float2(0.f, 0.f), a1 = a0, a2 = a0, a3 = a0;
#define ACC16(vv) { \
        float2 f0 = __half22float2(((const __half2*)&(vv))[0]); \
        float2 f1 = __half22float2(((const __half2*)&(vv))[1]); \
        float2 f2 = __half22float2(((const __half2*)&(vv))[2]); \
        float2 f3 = __half22float2(((const __half2*)&(vv))[3]); \
        a0.x += f0.x; a0.y += f0.y; a1.x += f1.x; a1.y += f1.y; \
        a2.x += f2.x; a2.y += f2.y; a3.x += f3.x; a3.y += f3.y; }
        int j = beg + g;
        for (; j + 4 < end; j += 8) {
            uint4 v0 = *(const uint4*)(in + (long long)csr[j] * 128 + t * 8);
            uint4 v1 = *(const uint4*)(in + (long long)csr[j + 4] * 128 + t * 8);
            ACC16(v0);
            ACC16(v1);
        }
        if (j < end) {
            uint4 v0 = *(const uint4*)(in + (long long)csr[j] * 128 + t * 8);
            ACC16(v0);
        }
#undef ACC16
        a0.x += __shfl_xor(a0.x, 16); a0.y += __shfl_xor(a0.y, 16);
        a1.x += __shfl_xor(a1.x, 16); a1.y += __shfl_xor(a1.y, 16);
        a2.x += __shfl_xor(a2.x, 16); a2.y += __shfl_xor(a2.y, 16);
        a3.x += __shfl_xor(a3.x, 16); a3.y += __shfl_xor(a3.y, 16);
        a0.x += __shfl_xor(a0.x, 32); a0.y += __shfl_xor(a0.y, 32);
        a1.x += __shfl_xor(a1.x, 32); a1.y += __shfl_xor(a1.y, 32);
        a2.x += __shfl_xor(a2.x, 32); a2.y += __shfl_xor(a2.y, 32);
        a3.x += __shfl_xor(a3.x, 32); a3.y += __shfl_xor(a3.y, 32);
        if (g == 0) {
            uint4 sv = *(const uint4*)(in + (long long)rc * 128 + t * 8);
            float2 f0 = __half22float2(((const __half2*)&sv)[0]);
            float2 f1 = __half22float2(((const __half2*)&sv)[1]);
            float2 f2 = __half22float2(((const __half2*)&sv)[2]);
            float2 f3 = __half22float2(((const __half2*)&sv)[3]);
            a0.x = fmaf(s, f0.x, a0.x); a0.y = fmaf(s, f0.y, a0.y);
            a1.x = fmaf(s, f1.x, a1.x); a1.y = fmaf(s, f1.y, a1.y);
            a2.x = fmaf(s, f2.x, a2.x); a2.y = fmaf(s, f2.y, a2.y);
            a3.x = fmaf(s, f3.x, a3.x); a3.y = fmaf(s, f3.y, a3.y);
            uint4 o;
            ((__half2*)&o)[0] = __float22half2_rn(a0);
            ((__half2*)&o)[1] = __float22half2_rn(a1);
            ((__half2*)&o)[2] = __float22half2_rn(a2);
            ((__half2*)&o)[3] = __float22half2_rn(a3);
            *(uint4*)&sA[row * 128 + ((t ^ (row & 15)) * 8)] = o;
        }
    }
    __syncthreads();

    // ---- Phase 2: MFMA MLP ----
    const int g16 = lane >> 4;
    const int r15 = lane & 15;

    f32x4 acc[2][8];
#pragma unroll
    for (int rt = 0; rt < 2; ++rt)
#pragma unroll
        for (int ct = 0; ct < 8; ++ct) acc[rt][ct] = (f32x4)0.f;

    // GEMM1
#pragma unroll
    for (int ks = 0; ks < 4; ++ks) {
        f16x8 wf[8];
#pragma unroll
        for (int ct = 0; ct < 8; ++ct)
            wf[ct] = *(const f16x8*)(pk1 + ((ks * 8 + ct) * 64 + lane) * 8);
#pragma unroll
        for (int rt = 0; rt < 2; ++rt) {
            int row = wave * 32 + rt * 16 + r15;
            f16x8 bf = *(const f16x8*)&sA[row * 128 + (((ks * 4 + g16) ^ r15) * 8)];
#pragma unroll
            for (int ct = 0; ct < 8; ++ct)
                acc[rt][ct] = __builtin_amdgcn_mfma_f32_16x16x32_f16(wf[ct], bf,
                                                                     acc[rt][ct], 0, 0, 0);
        }
    }

    __syncthreads();   // all reads of sA done -> safe to overwrite
    // epilogue 1: BN1 + ReLU -> fp16 back into swizzled sA
#pragma unroll
    for (int rt = 0; rt < 2; ++rt) {
        int row = wave * 32 + rt * 16 + r15;
#pragma unroll
        for (int ct = 0; ct < 8; ++ct) {
            int col = ct * 16 + g16 * 4;
            float4 sc4 = *(float4*)&sc1_s[col];
            float4 sh4 = *(float4*)&sh1_s[col];
            f32x4 a = acc[rt][ct];
            float o0 = fmaxf(fmaf(a[0], sc4.x, sh4.x), 0.f);
            float o1 = fmaxf(fmaf(a[1], sc4.y, sh4.y), 0.f);
            float o2 = fmaxf(fmaf(a[2], sc4.z, sh4.z), 0.f);
            float o3 = fmaxf(fmaf(a[3], sc4.w, sh4.w), 0.f);
            H4 h;
            h.a = __float22half2_rn(make_float2(o0, o1));
            h.b = __float22half2_rn(make_float2(o2, o3));
            int c = col >> 3;
            *(H4*)&sA[row * 128 + ((c ^ (row & 15)) * 8) + (col & 7)] = h;
        }
    }
    __syncthreads();

    // GEMM2
#pragma unroll
    for (int rt = 0; rt < 2; ++rt)
#pragma unroll
        for (int ct = 0; ct < 8; ++ct) acc[rt][ct] = (f32x4)0.f;
#pragma unroll
    for (int ks = 0; ks < 4; ++ks) {
        f16x8 wf[8];
#pragma unroll
        for (int ct = 0; ct < 8; ++ct)
            wf[ct] = *(const f16x8*)(pk2 + ((ks * 8 + ct) * 64 + lane) * 8);
#pragma unroll
        for (int rt = 0; rt < 2; ++rt) {
            int row = wave * 32 + rt * 16 + r15;
            f16x8 bf = *(const f16x8*)&sA[row * 128 + (((ks * 4 + g16) ^ r15) * 8)];
#pragma unroll
            for (int ct = 0; ct < 8; ++ct)
                acc[rt][ct] = __builtin_amdgcn_mfma_f32_16x16x32_f16(wf[ct], bf,
                                                                     acc[rt][ct], 0, 0, 0);
        }
    }

    // epilogue 2: BN2 + ReLU -> global fp16
#pragma unroll
    for (int rt = 0; rt < 2; ++rt) {
        int r = base + wave * 32 + rt * 16 + r15;
        if (r < N) {
            __half* orow = out + r * 128;
#pragma unroll
            for (int ct = 0; ct < 8; ++ct) {
                int col = ct * 16 + g16 * 4;
                float4 sc4 = *(float4*)&sc2_s[col];
                float4 sh4 = *(float4*)&sh2_s[col];
                f32x4 a = acc[rt][ct];
                float o0 = fmaxf(fmaf(a[0], sc4.x, sh4.x), 0.f);
                float o1 = fmaxf(fmaf(a[1], sc4.y, sh4.y), 0.f);
                float o2 = fmaxf(fmaf(a[2], sc4.z, sh4.z), 0.f);
                float o3 = fmaxf(fmaf(a[3], sc4.w, sh4.w), 0.f);
                H4 h;
                h.a = __float22half2_rn(make_float2(o0, o1));
                h.b = __float22half2_rn(make_float2(o2, o3));
                *(H4*)(orow + col) = h;
            }
        }
    }
}

// ---------------------------------------------------------------------------
// Fused head: h = relu(in@lin1W+lin1b); logits = h@lin2W+lin2b; log_softmax.
__global__ __launch_bounds__(256) void lin1_head_kernel(
    const __half* __restrict__ in, const __half* __restrict__ pk1,
    const float* __restrict__ l1b, const float* __restrict__ l2W,
    const float* __restrict__ l2b, float* __restrict__ out, int N) {
    __shared__ __half sA[128 * 128];
    __shared__ float Wl[1280];
    __shared__ float bl[10];
    __shared__ float b1_s[128];

    const int tid = threadIdx.x;
    for (int i = tid; i < 1280; i += 256) Wl[i] = l2W[i];
    if (tid < 10) bl[tid] = l2b[tid];
    if (tid < 128) b1_s[tid] = l1b[tid];

    const int base = blockIdx.x * 128;
#pragma unroll
    for (int q = 0; q < 8; ++q) {
        int i = tid + q * 256;
        int row = i >> 4, c = i & 15;
        int r = base + row;
        if (r >= N) r = N - 1;
        uint4 v = *(const uint4*)(in + r * 128 + c * 8);
        *(uint4*)&sA[row * 128 + ((c ^ (row & 15)) * 8)] = v;
    }
    __syncthreads();

    const int wave = tid >> 6;
    const int lane = tid & 63;
    const int g16 = lane >> 4;
    const int r15 = lane & 15;

    f32x4 acc[2][8];
#pragma unroll
    for (int rt = 0; rt < 2; ++rt)
#pragma unroll
        for (int ct = 0; ct < 8; ++ct) acc[rt][ct] = (f32x4)0.f;

#pragma unroll
    for (int ks = 0; ks < 4; ++ks) {
        f16x8 wf[8];
#pragma unroll
        for (int ct = 0; ct < 8; ++ct)
            wf[ct] = *(const f16x8*)(pk1 + ((ks * 8 + ct) * 64 + lane) * 8);
#pragma unroll
        for (int rt = 0; rt < 2; ++rt) {
            int row = wave * 32 + rt * 16 + r15;
            f16x8 bf = *(const f16x8*)&sA[row * 128 + (((ks * 4 + g16) ^ r15) * 8)];
#pragma unroll
            for (int ct = 0; ct < 8; ++ct)
                acc[rt][ct] = __builtin_amdgcn_mfma_f32_16x16x32_f16(wf[ct], bf,
                                                                     acc[rt][ct], 0, 0, 0);
        }
    }

#pragma unroll
    for (int rt = 0; rt < 2; ++rt) {
        float p[10];
#pragma unroll
        for (int c = 0; c < 10; ++c) p[c] = 0.f;
#pragma unroll
        for (int ct = 0; ct < 8; ++ct) {
            int col0 = ct * 16 + g16 * 4;
#pragma unroll
            for (int j = 0; j < 4; ++j) {
                int col = col0 + j;
                float h = fmaxf(acc[rt][ct][j] + b1_s[col], 0.f);
#pragma unroll
                for (int c = 0; c < 10; ++c) p[c] = fmaf(h, Wl[col * 10 + c], p[c]);
            }
        }
#pragma unroll
        for (int c = 0; c < 10; ++c) {
            p[c] += __shfl_xor(p[c], 16);
            p[c] += __shfl_xor(p[c], 32);
        }
        int r = base + wave * 32 + rt * 16 + r15;
        if (g16 == 0 && r < N) {
            float mx = -1e30f;
#pragma unroll
            for (int c = 0; c < 10; ++c) {
                p[c] += bl[c];
                mx = fmaxf(mx, p[c]);
            }
            float sum = 0.f;
#pragma unroll
            for (int c = 0; c < 10; ++c) sum += expf(p[c] - mx);
            float lse = mx + logf(sum);
            float* orow = out + (long long)r * 10;
#pragma unroll
            for (int c = 0; c < 10; ++c) orow[c] = p[c] - lse;
        }
    }
}

// ---------------------------------------------------------------------------
extern "C" void kernel_launch(void* const* d_in, const int* in_sizes, int n_in,
                              void* d_out, int out_size, void* d_ws, size_t ws_size,
                              hipStream_t stream) {
    const float* x   = (const float*)d_in[0];
    const void*  eix = d_in[1];
    const float* eps = (const float*)d_in[2];
    const float* W1  = (const float*)d_in[3];
    const float* b1  = (const float*)d_in[4];
    const float* g1  = (const float*)d_in[5];
    const float* bb1 = (const float*)d_in[6];
    const float* m1  = (const float*)d_in[7];
    const float* v1  = (const float*)d_in[8];
    const float* W2  = (const float*)d_in[9];
    const float* b2  = (const float*)d_in[10];
    const float* g2  = (const float*)d_in[11];
    const float* bb2 = (const float*)d_in[12];
    const float* m2  = (const float*)d_in[13];
    const float* v2  = (const float*)d_in[14];
    const float* l1W = (const float*)d_in[15];
    const float* l1b = (const float*)d_in[16];
    const float* l2W = (const float*)d_in[17];
    const float* l2b = (const float*)d_in[18];

    const int N = in_sizes[0] / 128;
    const long long E = in_sizes[1] / 2;
    const int NB = (N + 255) >> 8;            // 256-node buckets (<=512)

    // workspace layout (16B-aligned blocks first)
    __half* bufA  = (__half*)d_ws;                     // N*128 fp16
    __half* bufB  = bufA + (size_t)N * 128;            // N*128 fp16
    __half* pk    = bufB + (size_t)N * 128;            // 7*16384 fp16
    uint2*  bdata = (uint2*)(pk + 7 * 16384);          // E pairs (8B)
    int* csr_src  = (int*)(bdata + E);                 // E
    int* row_ptr  = csr_src + E;                       // N+1
    int* cnt_mat  = row_ptr + N + 1;                   // MAXNB*PB
    int* btotal   = cnt_mat + MAXNB * PB;              // MAXNB
    int* bbase    = btotal + MAXNB;                    // MAXNB
    int* boff     = bbase + MAXNB;                     // MAXNB+1
    int* flag     = boff + MAXNB + 1;                  // 1

    detect_idx_kernel<<<1, 256, 0, stream>>>((const unsigned int*)eix,
                                             (E < 2048 ? E : 2048), flag);

    p1_hist_kernel<<<PB, 256, 0, stream>>>(eix, E, flag, cnt_mat, NB);
    scan_bucket_kernel<<<NB, 256, 0, stream>>>(cnt_mat, btotal);
    scan_btotal_kernel<<<1, 512, 0, stream>>>(btotal, bbase, boff, NB, N, E, row_ptr);
    p2_scatter_kernel<<<PB, 256, 0, stream>>>(eix, E, flag, cnt_mat, bbase, bdata, NB);
    csr_build_kernel<<<NB, 256, 0, stream>>>(bdata, boff, N, row_ptr, csr_src);

    convert_x_kernel<<<2048, 256, 0, stream>>>(bufA, x, N * 32);
    pack_w_kernel<<<(7 * 2048 + 255) / 256, 256, 0, stream>>>(pk, W1, W2, l1W);

    const int mBlocks = (N + 127) / 128;

    __half* cur = bufA;
    __half* oth = bufB;
    for (int l = 0; l < 3; ++l) {
        gin_layer_kernel<<<mBlocks, 256, 0, stream>>>(
            cur, row_ptr, csr_src, eps, l,
            pk + (size_t)l * 16384, b1 + l * 128, g1 + l * 128, bb1 + l * 128,
            m1 + l * 128, v1 + l * 128,
            pk + (size_t)(3 + l) * 16384, b2 + l * 128, g2 + l * 128, bb2 + l * 128,
            m2 + l * 128, v2 + l * 128,
            oth, N);
        __half* t = cur; cur = oth; oth = t;
    }
    // fused lin1 + ReLU + lin2 + log_softmax
    lin1_head_kernel<<<mBlocks, 256, 0, stream>>>(
        cur, pk + (size_t)6 * 16384, l1b, l2W, l2b, (float*)d_out, N);
}

// Round 12
// 331.789 us; speedup vs baseline: 1.9657x; 1.9657x over previous
//
#include <hip/hip_runtime.h>
#include <hip/hip_fp16.h>

// GIN: 3 layers of {CSR-gather aggregate fused with (1+eps)*x, fused MLP(2x GEMM128 via
// MFMA, BN folded, ReLU)}, head fused into layer-3 MLP kernel.
// N=100000, E=1.6M. Round 12: revert round-11 gather fusion (latency-starved);
// pack bdata to 4B/edge ((src<<8)|dst&255); fuse lin1+lin2+log_softmax into the
// layer-3 MLP kernel (saves a 51MB round-trip + launch).

#define PB 256    // partition blocks
#define MAXNB 512 // max buckets (N <= 131072; src must fit 24 bits for packing)

typedef _Float16 f16x8 __attribute__((ext_vector_type(8)));
typedef float f32x4 __attribute__((ext_vector_type(4)));

struct H4 { __half2 a, b; };   // 8B fp16 quad

// ---------------------------------------------------------------------------
// Detect whether edge_index is int64 (all high words zero) or int32.
__global__ void detect_idx_kernel(const unsigned int* __restrict__ w, long long nOdd,
                                  int* __restrict__ flag) {
    __shared__ int any;
    if (threadIdx.x == 0) any = 0;
    __syncthreads();
    for (long long i = threadIdx.x; i < nOdd; i += blockDim.x) {
        if (w[2 * i + 1] != 0u) { any = 1; break; }
    }
    __syncthreads();
    if (threadIdx.x == 0) *flag = (any == 0) ? 1 : 0;   // 1 => int64 layout
}

// ---------------------------------------------------------------------------
// Pass 1: per-block LDS histogram over 256-node buckets -> cnt_mat[bucket][block].
__global__ __launch_bounds__(256) void p1_hist_kernel(
    const void* __restrict__ idx, long long E, const int* __restrict__ flag,
    int* __restrict__ cnt_mat, int NB) {
    __shared__ int h[MAXNB];
    for (int i = threadIdx.x; i < MAXNB; i += 256) h[i] = 0;
    __syncthreads();
    const long long C = (E + PB - 1) / PB;
    const long long lo = (long long)blockIdx.x * C;
    long long hi = lo + C; if (hi > E) hi = E;
    if (*flag) {
        const long long* pd = (const long long*)idx + E;
        for (long long i = lo + threadIdx.x; i < hi; i += 256)
            atomicAdd(&h[((int)pd[i]) >> 8], 1);
    } else {
        const int* pd = (const int*)idx + E;
        for (long long i = lo + threadIdx.x; i < hi; i += 256)
            atomicAdd(&h[pd[i] >> 8], 1);
    }
    __syncthreads();
    for (int i = threadIdx.x; i < NB; i += 256)
        cnt_mat[i * PB + blockIdx.x] = h[i];
}

// ---------------------------------------------------------------------------
// Per-bucket exclusive scan over the PB block-counts (in place) + bucket total.
__global__ __launch_bounds__(256) void scan_bucket_kernel(
    int* __restrict__ cnt_mat, int* __restrict__ btotal) {
    int k = blockIdx.x, t = threadIdx.x;
    __shared__ int sh[PB];
    int c = cnt_mat[k * PB + t];
    sh[t] = c;
    __syncthreads();
    for (int off = 1; off < PB; off <<= 1) {
        int v = (t >= off) ? sh[t - off] : 0;
        __syncthreads();
        sh[t] += v;
        __syncthreads();
    }
    cnt_mat[k * PB + t] = sh[t] - c;        // exclusive within bucket
    if (t == PB - 1) btotal[k] = sh[t];
}

// ---------------------------------------------------------------------------
// Exclusive scan of bucket totals -> bbase, boff; row_ptr[N] = E.
__global__ __launch_bounds__(512) void scan_btotal_kernel(
    const int* __restrict__ btotal, int* __restrict__ bbase, int* __restrict__ boff,
    int NB, int N, long long E, int* __restrict__ row_ptr) {
    int t = threadIdx.x;
    __shared__ int sh[512];
    int c = (t < NB) ? btotal[t] : 0;
    sh[t] = c;
    __syncthreads();
    for (int off = 1; off < 512; off <<= 1) {
        int v = (t >= off) ? sh[t - off] : 0;
        __syncthreads();
        sh[t] += v;
        __syncthreads();
    }
    int excl = sh[t] - c;
    if (t < NB) { bbase[t] = excl; boff[t] = excl; }
    if (t == 0) { boff[NB] = (int)E; row_ptr[N] = (int)E; }
}

// ---------------------------------------------------------------------------
// Pass 2: re-read chunk, LDS cursors seeded with global dense offsets, scatter
// packed (src<<8 | dst&255) into bucket-grouped bdata. 4B/edge, no global atomics.
__global__ __launch_bounds__(256) void p2_scatter_kernel(
    const void* __restrict__ idx, long long E, const int* __restrict__ flag,
    const int* __restrict__ cnt_mat, const int* __restrict__ bbase,
    unsigned* __restrict__ bdata, int NB) {
    __shared__ int cur[MAXNB];
    int b = blockIdx.x;
    for (int i = threadIdx.x; i < NB; i += 256)
        cur[i] = cnt_mat[i * PB + b] + bbase[i];
    __syncthreads();
    const long long C = (E + PB - 1) / PB;
    const long long lo = (long long)b * C;
    long long hi = lo + C; if (hi > E) hi = E;
    if (*flag) {
        const long long* ps = (const long long*)idx;
        const long long* pd = ps + E;
        for (long long i = lo + threadIdx.x; i < hi; i += 256) {
            int s = (int)ps[i], d = (int)pd[i];
            int r = atomicAdd(&cur[d >> 8], 1);
            bdata[r] = ((unsigned)s << 8) | (unsigned)(d & 255);
        }
    } else {
        const int* ps = (const int*)idx;
        const int* pd = ps + E;
        for (long long i = lo + threadIdx.x; i < hi; i += 256) {
            int s = ps[i], d = pd[i];
            int r = atomicAdd(&cur[d >> 8], 1);
            bdata[r] = ((unsigned)s << 8) | (unsigned)(d & 255);
        }
    }
}

// ---------------------------------------------------------------------------
// Per-bucket CSR finalize (256 nodes/bucket): LDS hist, LDS scan, row_ptr write,
// then place src into csr_src (16KB window per bucket, L2-absorbed).
__global__ __launch_bounds__(256) void csr_build_kernel(
    const unsigned* __restrict__ bdata, const int* __restrict__ boff, int N,
    int* __restrict__ row_ptr, int* __restrict__ csr_src) {
    int b = blockIdx.x, t = threadIdx.x;
    int lo = boff[b], hi = boff[b + 1];
    int nb = b << 8;
    __shared__ int cnt[256];
    __shared__ int sh[256];
    cnt[t] = 0;
    __syncthreads();
    for (int i = lo + t; i < hi; i += 256)
        atomicAdd(&cnt[bdata[i] & 255], 1);
    __syncthreads();
    int c = cnt[t];
    sh[t] = c;
    __syncthreads();
    for (int off = 1; off < 256; off <<= 1) {
        int v = (t >= off) ? sh[t - off] : 0;
        __syncthreads();
        sh[t] += v;
        __syncthreads();
    }
    int excl = sh[t] - c;
    if (nb + t < N) row_ptr[nb + t] = lo + excl;
    cnt[t] = excl;                 // cursor: local absolute position
    __syncthreads();
    for (int i = lo + t; i < hi; i += 256) {
        unsigned e = bdata[i];
        int p = atomicAdd(&cnt[e & 255], 1);
        csr_src[lo + p] = (int)(e >> 8);
    }
}

// ---------------------------------------------------------------------------
// x fp32 [N,128] -> fp16.
__global__ void convert_x_kernel(__half* __restrict__ out, const float* __restrict__ in,
                                 int n4) {
    int i = blockIdx.x * blockDim.x + threadIdx.x;
    int stride = gridDim.x * blockDim.x;
    const float4* in4 = (const float4*)in;
    for (; i < n4; i += stride) {
        float4 v = in4[i];
        H4 h;
        h.a = __float22half2_rn(make_float2(v.x, v.y));
        h.b = __float22half2_rn(make_float2(v.z, v.w));
        *(H4*)(out + i * 4) = h;
    }
}

// ---------------------------------------------------------------------------
// Pack 7 fp32 [128][128] weight matrices (W1 l0..2, W2 l0..2, lin1) into fp16
// MFMA "A-operand" fragment order: pk[mat][((ks*8+ct)*64+lane)*8 + j] =
//   W[ks*32 + (lane>>4)*8 + j][ct*16 + (lane&15)]
__global__ void pack_w_kernel(__half* __restrict__ pk, const float* __restrict__ W1,
                              const float* __restrict__ W2, const float* __restrict__ lin1) {
    int t = blockIdx.x * blockDim.x + threadIdx.x;
    if (t >= 7 * 2048) return;
    int mat = t >> 11;
    int rem = t & 2047;
    int ks = rem >> 9;
    int ct = (rem >> 6) & 7;
    int lane = rem & 63;
    int g = lane >> 4, c = lane & 15;
    const float* src = (mat < 3) ? W1 + mat * 16384
                     : (mat < 6) ? W2 + (mat - 3) * 16384
                                 : lin1;
    __half* dst = pk + mat * 16384 + ((size_t)((ks * 8 + ct) * 64 + lane)) * 8;
#pragma unroll
    for (int j = 0; j < 8; ++j)
        dst[j] = (__half)src[(ks * 32 + g * 8 + j) * 128 + ct * 16 + c];
}

// ---------------------------------------------------------------------------
// out[n] = fp16( (1+eps)*x[n] + sum_j x[csr[j]] ), fp32 accumulate.
// Wave = 4 groups x 16 lanes; uint4 (16B) row chunks; cross-group shfl reduce.
__global__ __launch_bounds__(256) void gather_h_kernel(
    __half* __restrict__ out, const __half* __restrict__ x,
    const int* __restrict__ row_ptr, const int* __restrict__ csr,
    const float* __restrict__ eps, int layer, int N) {
    int wave = threadIdx.x >> 6;
    int lane = threadIdx.x & 63;
    int g = lane >> 4;          // neighbor sub-group
    int t = lane & 15;          // 16B chunk within row
    int wid = blockIdx.x * 4 + wave;
    int nw = gridDim.x * 4;
    float s = 1.0f + eps[layer];
    for (int n = wid; n < N; n += nw) {
        int beg = row_ptr[n], end = row_ptr[n + 1];
        float2 a0 = make_float2(0.f, 0.f), a1 = a0, a2 = a0, a3 = a0;
#define ACC16(vv) { \
        float2 f0 = __half22float2(((const __half2*)&(vv))[0]); \
        float2 f1 = __half22float2(((const __half2*)&(vv))[1]); \
        float2 f2 = __half22float2(((const __half2*)&(vv))[2]); \
        float2 f3 = __half22float2(((const __half2*)&(vv))[3]); \
        a0.x += f0.x; a0.y += f0.y; a1.x += f1.x; a1.y += f1.y; \
        a2.x += f2.x; a2.y += f2.y; a3.x += f3.x; a3.y += f3.y; }
        int j = beg + g;
        for (; j + 4 < end; j += 8) {
            uint4 v0 = *(const uint4*)(x + (long long)csr[j] * 128 + t * 8);
            uint4 v1 = *(const uint4*)(x + (long long)csr[j + 4] * 128 + t * 8);
            ACC16(v0);
            ACC16(v1);
        }
        if (j < end) {
            uint4 v0 = *(const uint4*)(x + (long long)csr[j] * 128 + t * 8);
            ACC16(v0);
        }
#undef ACC16
        a0.x += __shfl_xor(a0.x, 16); a0.y += __shfl_xor(a0.y, 16);
        a1.x += __shfl_xor(a1.x, 16); a1.y += __shfl_xor(a1.y, 16);
        a2.x += __shfl_xor(a2.x, 16); a2.y += __shfl_xor(a2.y, 16);
        a3.x += __shfl_xor(a3.x, 16); a3.y += __shfl_xor(a3.y, 16);
        a0.x += __shfl_xor(a0.x, 32); a0.y += __shfl_xor(a0.y, 32);
        a1.x += __shfl_xor(a1.x, 32); a1.y += __shfl_xor(a1.y, 32);
        a2.x += __shfl_xor(a2.x, 32); a2.y += __shfl_xor(a2.y, 32);
        a3.x += __shfl_xor(a3.x, 32); a3.y += __shfl_xor(a3.y, 32);
        if (g == 0) {
            uint4 sv = *(const uint4*)(x + (long long)n * 128 + t * 8);
            float2 f0 = __half22float2(((const __half2*)&sv)[0]);
            float2 f1 = __half22float2(((const __half2*)&sv)[1]);
            float2 f2 = __half22float2(((const __half2*)&sv)[2]);
            float2 f3 = __half22float2(((const __half2*)&sv)[3]);
            a0.x = fmaf(s, f0.x, a0.x); a0.y = fmaf(s, f0.y, a0.y);
            a1.x = fmaf(s, f1.x, a1.x); a1.y = fmaf(s, f1.y, a1.y);
            a2.x = fmaf(s, f2.x, a2.x); a2.y = fmaf(s, f2.y, a2.y);
            a3.x = fmaf(s, f3.x, a3.x); a3.y = fmaf(s, f3.y, a3.y);
            uint4 o;
            ((__half2*)&o)[0] = __float22half2_rn(a0);
            ((__half2*)&o)[1] = __float22half2_rn(a1);
            ((__half2*)&o)[2] = __float22half2_rn(a2);
            ((__half2*)&o)[3] = __float22half2_rn(a3);
            *(uint4*)(out + (long long)n * 128 + t * 8) = o;
        }
    }
}

// ---------------------------------------------------------------------------
// Shared MFMA helpers (macro bodies keep register pressure identical to r10).
// GEMM from swizzled sA with packed weights pkX into acc.
#define MFMA_GEMM(PK)                                                          \
    _Pragma("unroll")                                                          \
    for (int rt = 0; rt < 2; ++rt)                                             \
        _Pragma("unroll")                                                      \
        for (int ct = 0; ct < 8; ++ct) acc[rt][ct] = (f32x4)0.f;               \
    _Pragma("unroll")                                                          \
    for (int ks = 0; ks < 4; ++ks) {                                           \
        f16x8 wf[8];                                                           \
        _Pragma("unroll")                                                      \
        for (int ct = 0; ct < 8; ++ct)                                         \
            wf[ct] = *(const f16x8*)((PK) + ((ks * 8 + ct) * 64 + lane) * 8);  \
        _Pragma("unroll")                                                      \
        for (int rt = 0; rt < 2; ++rt) {                                       \
            int row = wave * 32 + rt * 16 + r15;                               \
            f16x8 bf = *(const f16x8*)&sA[row * 128 + (((ks * 4 + g16) ^ r15) * 8)]; \
            _Pragma("unroll")                                                  \
            for (int ct = 0; ct < 8; ++ct)                                     \
                acc[rt][ct] = __builtin_amdgcn_mfma_f32_16x16x32_f16(wf[ct], bf, \
                                                                     acc[rt][ct], 0, 0, 0); \
        }                                                                      \
    }

// BN+ReLU epilogue from acc back into swizzled sA (fp16).
#define EPI_TO_LDS(SC, SH)                                                     \
    _Pragma("unroll")                                                          \
    for (int rt = 0; rt < 2; ++rt) {                                           \
        int row = wave * 32 + rt * 16 + r15;                                   \
        _Pragma("unroll")                                                      \
        for (int ct = 0; ct < 8; ++ct) {                                       \
            int col = ct * 16 + g16 * 4;                                       \
            float4 sc4 = *(float4*)&(SC)[col];                                 \
            float4 sh4 = *(float4*)&(SH)[col];                                 \
            f32x4 a = acc[rt][ct];                                             \
            float o0 = fmaxf(fmaf(a[0], sc4.x, sh4.x), 0.f);                   \
            float o1 = fmaxf(fmaf(a[1], sc4.y, sh4.y), 0.f);                   \
            float o2 = fmaxf(fmaf(a[2], sc4.z, sh4.z), 0.f);                   \
            float o3 = fmaxf(fmaf(a[3], sc4.w, sh4.w), 0.f);                   \
            H4 h;                                                              \
            h.a = __float22half2_rn(make_float2(o0, o1));                      \
            h.b = __float22half2_rn(make_float2(o2, o3));                      \
            int cc = col >> 3;                                                 \
            *(H4*)&sA[row * 128 + ((cc ^ (row & 15)) * 8) + (col & 7)] = h;    \
        }                                                                      \
    }

// ---------------------------------------------------------------------------
// Fused MLP (layers 1-2): out = relu(BN2(relu(BN1(in@W1+b1))@W2+b2)).
__global__ __launch_bounds__(256) void gemm12_h_kernel(
    const __half* __restrict__ in,
    const __half* __restrict__ pk1, const float* __restrict__ b1,
    const float* __restrict__ g1, const float* __restrict__ bb1,
    const float* __restrict__ m1, const float* __restrict__ v1,
    const __half* __restrict__ pk2, const float* __restrict__ b2,
    const float* __restrict__ g2, const float* __restrict__ bb2,
    const float* __restrict__ m2, const float* __restrict__ v2,
    __half* __restrict__ out, int N) {
    __shared__ __half sA[128 * 128];
    __shared__ float sc1_s[128], sh1_s[128], sc2_s[128], sh2_s[128];

    const int tid = threadIdx.x;
    if (tid < 128) {
        int c = tid;
        float sc = g1[c] * rsqrtf(v1[c] + 1e-5f);
        sc1_s[c] = sc;
        sh1_s[c] = b1[c] * sc + bb1[c] - m1[c] * sc;
        sc = g2[c] * rsqrtf(v2[c] + 1e-5f);
        sc2_s[c] = sc;
        sh2_s[c] = b2[c] * sc + bb2[c] - m2[c] * sc;
    }

    const int base = blockIdx.x * 128;
#pragma unroll
    for (int q = 0; q < 8; ++q) {
        int i = tid + q * 256;
        int row = i >> 4, c = i & 15;
        int r = base + row;
        if (r >= N) r = N - 1;
        uint4 v = *(const uint4*)(in + r * 128 + c * 8);
        *(uint4*)&sA[row * 128 + ((c ^ (row & 15)) * 8)] = v;
    }
    __syncthreads();

    const int wave = tid >> 6;
    const int lane = tid & 63;
    const int g16 = lane >> 4;
    const int r15 = lane & 15;

    f32x4 acc[2][8];
    MFMA_GEMM(pk1);
    __syncthreads();
    EPI_TO_LDS(sc1_s, sh1_s);
    __syncthreads();
    MFMA_GEMM(pk2);

    // epilogue 2: BN2 + ReLU -> global fp16
#pragma unroll
    for (int rt = 0; rt < 2; ++rt) {
        int r = base + wave * 32 + rt * 16 + r15;
        if (r < N) {
            __half* orow = out + r * 128;
#pragma unroll
            for (int ct = 0; ct < 8; ++ct) {
                int col = ct * 16 + g16 * 4;
                float4 sc4 = *(float4*)&sc2_s[col];
                float4 sh4 = *(float4*)&sh2_s[col];
                f32x4 a = acc[rt][ct];
                float o0 = fmaxf(fmaf(a[0], sc4.x, sh4.x), 0.f);
                float o1 = fmaxf(fmaf(a[1], sc4.y, sh4.y), 0.f);
                float o2 = fmaxf(fmaf(a[2], sc4.z, sh4.z), 0.f);
                float o3 = fmaxf(fmaf(a[3], sc4.w, sh4.w), 0.f);
                H4 h;
                h.a = __float22half2_rn(make_float2(o0, o1));
                h.b = __float22half2_rn(make_float2(o2, o3));
                *(H4*)(orow + col) = h;
            }
        }
    }
}

// ---------------------------------------------------------------------------
// Layer-3 MLP + head fused: x3 = relu(BN2(relu(BN1(in@W1))@W2)) -> LDS;
// h = relu(x3@lin1W+lin1b); logits = h@lin2W+lin2b; out = log_softmax.
__global__ __launch_bounds__(256) void gemm12_head_kernel(
    const __half* __restrict__ in,
    const __half* __restrict__ pk1, const float* __restrict__ b1,
    const float* __restrict__ g1, const float* __restrict__ bb1,
    const float* __restrict__ m1, const float* __restrict__ v1,
    const __half* __restrict__ pk2, const float* __restrict__ b2,
    const float* __restrict__ g2, const float* __restrict__ bb2,
    const float* __restrict__ m2, const float* __restrict__ v2,
    const __half* __restrict__ pk3, const float* __restrict__ l1b,
    const float* __restrict__ l2W, const float* __restrict__ l2b,
    float* __restrict__ out, int N) {
    __shared__ __half sA[128 * 128];
    __shared__ float sc1_s[128], sh1_s[128], sc2_s[128], sh2_s[128];
    __shared__ float Wl[1280];
    __shared__ float bl[10];
    __shared__ float b1_s[128];

    const int tid = threadIdx.x;
    if (tid < 128) {
        int c = tid;
        float sc = g1[c] * rsqrtf(v1[c] + 1e-5f);
        sc1_s[c] = sc;
        sh1_s[c] = b1[c] * sc + bb1[c] - m1[c] * sc;
        sc = g2[c] * rsqrtf(v2[c] + 1e-5f);
        sc2_s[c] = sc;
        sh2_s[c] = b2[c] * sc + bb2[c] - m2[c] * sc;
        b1_s[c] = l1b[c];
    }
    for (int i = tid; i < 1280; i += 256) Wl[i] = l2W[i];
    if (tid < 10) bl[tid] = l2b[tid];

    const int base = blockIdx.x * 128;
#pragma unroll
    for (int q = 0; q < 8; ++q) {
        int i = tid + q * 256;
        int row = i >> 4, c = i & 15;
        int r = base + row;
        if (r >= N) r = N - 1;
        uint4 v = *(const uint4*)(in + r * 128 + c * 8);
        *(uint4*)&sA[row * 128 + ((c ^ (row & 15)) * 8)] = v;
    }
    __syncthreads();

    const int wave = tid >> 6;
    const int lane = tid & 63;
    const int g16 = lane >> 4;
    const int r15 = lane & 15;

    f32x4 acc[2][8];
    MFMA_GEMM(pk1);
    __syncthreads();
    EPI_TO_LDS(sc1_s, sh1_s);
    __syncthreads();
    MFMA_GEMM(pk2);
    __syncthreads();
    EPI_TO_LDS(sc2_s, sh2_s);      // x3 (layer-3 output) back to LDS
    __syncthreads();
    MFMA_GEMM(pk3);                // lin1 (no BN)

    // head: h = relu(acc + l1b); partial logits; cross-group reduce; softmax
#pragma unroll
    for (int rt = 0; rt < 2; ++rt) {
        float p[10];
#pragma unroll
        for (int c = 0; c < 10; ++c) p[c] = 0.f;
#pragma unroll
        for (int ct = 0; ct < 8; ++ct) {
            int col0 = ct * 16 + g16 * 4;
#pragma unroll
            for (int j = 0; j < 4; ++j) {
                int col = col0 + j;
                float h = fmaxf(acc[rt][ct][j] + b1_s[col], 0.f);
#pragma unroll
                for (int c = 0; c < 10; ++c) p[c] = fmaf(h, Wl[col * 10 + c], p[c]);
            }
        }
#pragma unroll
        for (int c = 0; c < 10; ++c) {
            p[c] += __shfl_xor(p[c], 16);
            p[c] += __shfl_xor(p[c], 32);
        }
        int r = base + wave * 32 + rt * 16 + r15;
        if (g16 == 0 && r < N) {
            float mx = -1e30f;
#pragma unroll
            for (int c = 0; c < 10; ++c) {
                p[c] += bl[c];
                mx = fmaxf(mx, p[c]);
            }
            float sum = 0.f;
#pragma unroll
            for (int c = 0; c < 10; ++c) sum += expf(p[c] - mx);
            float lse = mx + logf(sum);
            float* orow = out + (long long)r * 10;
#pragma unroll
            for (int c = 0; c < 10; ++c) orow[c] = p[c] - lse;
        }
    }
}

// ---------------------------------------------------------------------------
extern "C" void kernel_launch(void* const* d_in, const int* in_sizes, int n_in,
                              void* d_out, int out_size, void* d_ws, size_t ws_size,
                              hipStream_t stream) {
    const float* x   = (const float*)d_in[0];
    const void*  eix = d_in[1];
    const float* eps = (const float*)d_in[2];
    const float* W1  = (const float*)d_in[3];
    const float* b1  = (const float*)d_in[4];
    const float* g1  = (const float*)d_in[5];
    const float* bb1 = (const float*)d_in[6];
    const float* m1  = (const float*)d_in[7];
    const float* v1  = (const float*)d_in[8];
    const float* W2  = (const float*)d_in[9];
    const float* b2  = (const float*)d_in[10];
    const float* g2  = (const float*)d_in[11];
    const float* bb2 = (const float*)d_in[12];
    const float* m2  = (const float*)d_in[13];
    const float* v2  = (const float*)d_in[14];
    const float* l1W = (const float*)d_in[15];
    const float* l1b = (const float*)d_in[16];
    const float* l2W = (const float*)d_in[17];
    const float* l2b = (const float*)d_in[18];

    const int N = in_sizes[0] / 128;
    const long long E = in_sizes[1] / 2;
    const int NB = (N + 255) >> 8;            // 256-node buckets (<=512)

    // workspace layout (16B-aligned blocks first)
    __half* bufA  = (__half*)d_ws;                     // N*128 fp16
    __half* bufB  = bufA + (size_t)N * 128;            // N*128 fp16
    __half* pk    = bufB + (size_t)N * 128;            // 7*16384 fp16
    unsigned* bdata = (unsigned*)(pk + 7 * 16384);     // E packed (4B)
    int* csr_src  = (int*)(bdata + E);                 // E
    int* row_ptr  = csr_src + E;                       // N+1
    int* cnt_mat  = row_ptr + N + 1;                   // MAXNB*PB
    int* btotal   = cnt_mat + MAXNB * PB;              // MAXNB
    int* bbase    = btotal + MAXNB;                    // MAXNB
    int* boff     = bbase + MAXNB;                     // MAXNB+1
    int* flag     = boff + MAXNB + 1;                  // 1

    detect_idx_kernel<<<1, 256, 0, stream>>>((const unsigned int*)eix,
                                             (E < 2048 ? E : 2048), flag);

    p1_hist_kernel<<<PB, 256, 0, stream>>>(eix, E, flag, cnt_mat, NB);
    scan_bucket_kernel<<<NB, 256, 0, stream>>>(cnt_mat, btotal);
    scan_btotal_kernel<<<1, 512, 0, stream>>>(btotal, bbase, boff, NB, N, E, row_ptr);
    p2_scatter_kernel<<<PB, 256, 0, stream>>>(eix, E, flag, cnt_mat, bbase, bdata, NB);
    csr_build_kernel<<<NB, 256, 0, stream>>>(bdata, boff, N, row_ptr, csr_src);

    convert_x_kernel<<<2048, 256, 0, stream>>>(bufA, x, N * 32);
    pack_w_kernel<<<(7 * 2048 + 255) / 256, 256, 0, stream>>>(pk, W1, W2, l1W);

    const int gBlocks = 2048;
    const int mBlocks = (N + 127) / 128;

    __half* cur = bufA;
    __half* oth = bufB;
    for (int l = 0; l < 2; ++l) {
        gather_h_kernel<<<gBlocks, 256, 0, stream>>>(oth, cur, row_ptr, csr_src, eps, l, N);
        gemm12_h_kernel<<<mBlocks, 256, 0, stream>>>(
            oth,
            pk + (size_t)l * 16384, b1 + l * 128, g1 + l * 128, bb1 + l * 128,
            m1 + l * 128, v1 + l * 128,
            pk + (size_t)(3 + l) * 16384, b2 + l * 128, g2 + l * 128, bb2 + l * 128,
            m2 + l * 128, v2 + l * 128,
            oth, N);
        __half* t = cur; cur = oth; oth = t;
    }
    // layer 3: gather, then MLP + lin1 + lin2 + log_softmax fused -> d_out
    gather_h_kernel<<<gBlocks, 256, 0, stream>>>(oth, cur, row_ptr, csr_src, eps, 2, N);
    gemm12_head_kernel<<<mBlocks, 256, 0, stream>>>(
        oth,
        pk + (size_t)2 * 16384, b1 + 2 * 128, g1 + 2 * 128, bb1 + 2 * 128,
        m1 + 2 * 128, v1 + 2 * 128,
        pk + (size_t)5 * 16384, b2 + 2 * 128, g2 + 2 * 128, bb2 + 2 * 128,
        m2 + 2 * 128, v2 + 2 * 128,
        pk + (size_t)6 * 16384, l1b, l2W, l2b,
        (float*)d_out, N);
}